// Round 6
// baseline (103.631 us; speedup 1.0000x reference)
//
#include <hip/hip_runtime.h>
#include <math.h>

// feats (16384, 1024) fp32 -> scalar. Memory-bound reduction.
//   pair = N*sum(x*x) - dot(colsum,colsum); out = exp(-pair/count)
//
// Cost model (R5): harness replay traffic = restore 128 MB + ws poison 256 MB
// + our 64 MB read ~= 448 MB ~= 70 us floor. Stage1 runs at ~3.1 TB/s
// effective because its reads force writeback of the just-poisoned dirty L3
// lines (64 MB extra writes in our window) -- structural, mapping-independent
// (R4 blocked == R5 sweep). R6: cut a graph node by fusing stage2+finalize
// with the last-block-done pattern; stage1 unchanged (R4 mapping).

#define DIMC 1024
#define GRID_A 1024   // stage-1 blocks; rows/block = 16
#define ROWS_A 16
#define RED_BLOCKS 64 // fused stage-2 blocks; each reduces 16 P-rows

typedef float vf4 __attribute__((ext_vector_type(4)));

// ws layout (floats): P[GRID_A][DIMC] | SQ[GRID_A] | P2[RED_BLOCKS][DIMC] | cnt(uint)

__global__ __launch_bounds__(256) void stage1_kernel(const float* __restrict__ feats,
                                                     float* __restrict__ P,
                                                     float* __restrict__ SQ,
                                                     unsigned int* __restrict__ cnt) {
    const int t = threadIdx.x;          // owns float4-column t (cols 4t..4t+3)
    const int b = blockIdx.x;
    if (b == 0 && t == 0) cnt[0] = 0;   // zero the done-counter for stage2f
                                        // (kernel-boundary release makes it visible)
    const vf4* base = reinterpret_cast<const vf4*>(feats) + (size_t)b * (ROWS_A * 256) + t;
    vf4 v[ROWS_A];
    #pragma unroll
    for (int j = 0; j < ROWS_A; ++j)      // 16 independent 16B loads in flight
        v[j] = base[(size_t)j * 256];
    vf4 csum = v[0];
    float sq = v[0].x * v[0].x + v[0].y * v[0].y + v[0].z * v[0].z + v[0].w * v[0].w;
    #pragma unroll
    for (int j = 1; j < ROWS_A; ++j) {
        csum += v[j];
        sq += v[j].x * v[j].x + v[j].y * v[j].y + v[j].z * v[j].z + v[j].w * v[j].w;
    }
    reinterpret_cast<vf4*>(P)[(size_t)b * 256 + t] = csum;  // plain coalesced store
    for (int off = 32; off > 0; off >>= 1) sq += __shfl_down(sq, off, 64);
    __shared__ float wsum[4];
    if ((t & 63) == 0) wsum[t >> 6] = sq;
    __syncthreads();
    if (t == 0) SQ[b] = wsum[0] + wsum[1] + wsum[2] + wsum[3];
}

// Fused stage2 + finalize: 64 blocks reduce P -> P2; the last block to finish
// (device-scope counter) reduces P2 (L2/L3-hot 256 KB) + SQ and writes out.
__global__ __launch_bounds__(256) void stage2f_kernel(const float* __restrict__ P,
                                                      float* __restrict__ P2,
                                                      const float* __restrict__ SQ,
                                                      unsigned int* __restrict__ cnt,
                                                      float* __restrict__ out,
                                                      int nrows) {
    const int t = threadIdx.x;
    const int r = blockIdx.x;
    {
        const vf4* base = reinterpret_cast<const vf4*>(P) + (size_t)r * 16 * 256 + t;
        vf4 acc = base[0];
        #pragma unroll
        for (int i = 1; i < 16; ++i) acc += base[(size_t)i * 256];
        reinterpret_cast<vf4*>(P2)[(size_t)r * 256 + t] = acc;
    }
    // Publish P2 row, then check if we're last.
    __threadfence();                       // release: P2 row visible device-wide
    __shared__ int is_last;
    if (t == 0) is_last = (atomicAdd(cnt, 1u) == RED_BLOCKS - 1) ? 1 : 0;
    __syncthreads();
    if (!is_last) return;
    __threadfence();                       // acquire: see all other blocks' P2 rows

    // colsum quad t over 64 P2 rows -> partial dot; SQ partial via vf4.
    vf4 c = reinterpret_cast<const vf4*>(P2)[t];
    #pragma unroll 8
    for (int i = 1; i < RED_BLOCKS; ++i)
        c += reinterpret_cast<const vf4*>(P2)[(size_t)i * 256 + t];
    float s = c.x * c.x + c.y * c.y + c.z * c.z + c.w * c.w;
    vf4 qv = reinterpret_cast<const vf4*>(SQ)[t];   // SQ[1024] = 256 vf4
    float q = qv.x + qv.y + qv.z + qv.w;
    for (int off = 32; off > 0; off >>= 1) {
        s += __shfl_down(s, off, 64);
        q += __shfl_down(q, off, 64);
    }
    __shared__ float sdot[4], ssq[4];
    const int lane = t & 63, wave = t >> 6;
    if (lane == 0) { sdot[wave] = s; ssq[wave] = q; }
    __syncthreads();
    if (t == 0) {
        const float dot = sdot[0] + sdot[1] + sdot[2] + sdot[3];
        const float sqt = ssq[0] + ssq[1] + ssq[2] + ssq[3];
        const double pair = (double)nrows * (double)sqt - (double)dot;
        const double count = (double)nrows * (double)(nrows - 1) * 0.5;
        out[0] = (float)exp(-pair / count);
    }
}

// ---------------- fallback path (generic nrows): R1 atomic version ----------------
__global__ __launch_bounds__(256) void zero_ws_kernel(float* __restrict__ ws) {
    int idx = blockIdx.x * 256 + threadIdx.x;
    if (idx <= DIMC) ws[idx] = 0.0f;
}

__global__ __launch_bounds__(256) void partial_atomic_kernel(const float* __restrict__ feats,
                                                             float* __restrict__ ws,
                                                             int nrows) {
    const int t = threadIdx.x;
    const int col4 = t * 4;
    float4 csum = make_float4(0.f, 0.f, 0.f, 0.f);
    float sq = 0.f;
    for (int row = blockIdx.x; row < nrows; row += gridDim.x) {
        const float4 v = *reinterpret_cast<const float4*>(feats + (size_t)row * DIMC + col4);
        csum.x += v.x; csum.y += v.y; csum.z += v.z; csum.w += v.w;
        sq += v.x * v.x + v.y * v.y + v.z * v.z + v.w * v.w;
    }
    atomicAdd(&ws[col4 + 0], csum.x);
    atomicAdd(&ws[col4 + 1], csum.y);
    atomicAdd(&ws[col4 + 2], csum.z);
    atomicAdd(&ws[col4 + 3], csum.w);
    for (int off = 32; off > 0; off >>= 1) sq += __shfl_down(sq, off, 64);
    __shared__ float wsum[4];
    const int lane = t & 63, wave = t >> 6;
    if (lane == 0) wsum[wave] = sq;
    __syncthreads();
    if (t == 0) atomicAdd(&ws[DIMC], wsum[0] + wsum[1] + wsum[2] + wsum[3]);
}

__global__ __launch_bounds__(1024) void finalize_ws_kernel(const float* __restrict__ ws,
                                                           float* __restrict__ out,
                                                           int nrows) {
    const int t = threadIdx.x;
    float c = ws[t];
    float s = c * c;
    for (int off = 32; off > 0; off >>= 1) s += __shfl_down(s, off, 64);
    __shared__ float wsum[16];
    const int lane = t & 63, wave = t >> 6;
    if (lane == 0) wsum[wave] = s;
    __syncthreads();
    if (t == 0) {
        float dot = 0.f;
        #pragma unroll
        for (int i = 0; i < 16; ++i) dot += wsum[i];
        const double pair = (double)nrows * (double)ws[DIMC] - (double)dot;
        const double count = (double)nrows * (double)(nrows - 1) * 0.5;
        out[0] = (float)exp(-pair / count);
    }
}

extern "C" void kernel_launch(void* const* d_in, const int* in_sizes, int n_in,
                              void* d_out, int out_size, void* d_ws, size_t ws_size,
                              hipStream_t stream) {
    const float* feats = (const float*)d_in[0];
    float* out = (float*)d_out;
    float* ws = (float*)d_ws;
    const int nrows = in_sizes[0] / DIMC;

    float* P = ws;                                    // GRID_A*DIMC floats
    float* SQ = P + (size_t)GRID_A * DIMC;            // GRID_A floats
    float* P2 = SQ + GRID_A;                          // RED_BLOCKS*DIMC floats
    unsigned int* cnt = (unsigned int*)(P2 + (size_t)RED_BLOCKS * DIMC);
    const size_t need = ((size_t)GRID_A * DIMC + GRID_A + (size_t)RED_BLOCKS * DIMC + 1) * sizeof(float);

    if (nrows == GRID_A * ROWS_A && ws_size >= need) {
        stage1_kernel<<<GRID_A, 256, 0, stream>>>(feats, P, SQ, cnt);
        stage2f_kernel<<<RED_BLOCKS, 256, 0, stream>>>(P, P2, SQ, cnt, out, nrows);
    } else {
        zero_ws_kernel<<<(DIMC + 256) / 256, 256, 0, stream>>>(ws);
        partial_atomic_kernel<<<512, 256, 0, stream>>>(feats, ws, nrows);
        finalize_ws_kernel<<<1, 1024, 0, stream>>>(ws, out, nrows);
    }
}

// Round 7
// 95.034 us; speedup vs baseline: 1.0905x; 1.0905x over previous
//
#include <hip/hip_runtime.h>
#include <math.h>

// feats (16384, 1024) fp32 -> scalar. Memory-bound reduction.
//   pair = N*sum(x*x) - dot(colsum,colsum); out = exp(-pair/count)
//
// R7 = exact revert to R4 (best: 95.2 us).
// History: R3 nt-loads 2.2 TB/s (nt bypasses L3 of just-restored input) ->
// R4 plain loads ~3.1 TB/s effective; R5 grid-sweep row mapping neutral
// (DRAM-stream theory falsified); R6 stage2+finalize fusion via
// last-block-done REGRESSED +8.4 us (device-scope __threadfence = L2
// writeback/inv per block; cross-XCD visibility is expensive -- kernel
// boundary is the cheap release). Harness-fixed floor ~65-70 us: ws poison
// fill 42 us @6.4 TB/s (measured), feats restore ~20 us, node gaps.

#define DIMC 1024
#define GRID_A 1024   // stage-1 blocks; rows/block = 16384/1024 = 16
#define ROWS_A 16
#define RED_BLOCKS 64 // stage-2 blocks; each reduces 16 P-rows

typedef float vf4 __attribute__((ext_vector_type(4)));

// ---------------- main path (nrows == 16384), no atomics ----------------
// ws layout (floats): P[GRID_A][DIMC] | SQ[GRID_A] | P2[RED_BLOCKS][DIMC]

__global__ __launch_bounds__(256) void stage1_kernel(const float* __restrict__ feats,
                                                     float* __restrict__ P,
                                                     float* __restrict__ SQ) {
    const int t = threadIdx.x;          // owns float4-column t (cols 4t..4t+3)
    const int b = blockIdx.x;
    const vf4* base = reinterpret_cast<const vf4*>(feats) + (size_t)b * (ROWS_A * 256) + t;
    vf4 v[ROWS_A];
    #pragma unroll
    for (int j = 0; j < ROWS_A; ++j)      // 16 independent 16B loads in flight
        v[j] = base[(size_t)j * 256];     // plain loads (L3 serves restored input)
    vf4 csum = v[0];
    float sq = v[0].x * v[0].x + v[0].y * v[0].y + v[0].z * v[0].z + v[0].w * v[0].w;
    #pragma unroll
    for (int j = 1; j < ROWS_A; ++j) {
        csum += v[j];
        sq += v[j].x * v[j].x + v[j].y * v[j].y + v[j].z * v[j].z + v[j].w * v[j].w;
    }
    reinterpret_cast<vf4*>(P)[(size_t)b * 256 + t] = csum;  // plain coalesced store
    for (int off = 32; off > 0; off >>= 1) sq += __shfl_down(sq, off, 64);
    __shared__ float wsum[4];
    if ((t & 63) == 0) wsum[t >> 6] = sq;
    __syncthreads();
    if (t == 0) SQ[b] = wsum[0] + wsum[1] + wsum[2] + wsum[3];  // plain store
}

// 64 blocks: block r sums P rows 16r..16r+15 -> P2[r][*]. Plain stores.
__global__ __launch_bounds__(256) void stage2_kernel(const float* __restrict__ P,
                                                     float* __restrict__ P2) {
    const int t = threadIdx.x;
    const int r = blockIdx.x;
    const vf4* base = reinterpret_cast<const vf4*>(P) + (size_t)r * 16 * 256 + t;
    vf4 acc = base[0];
    #pragma unroll
    for (int i = 1; i < 16; ++i) acc += base[(size_t)i * 256];
    reinterpret_cast<vf4*>(P2)[(size_t)r * 256 + t] = acc;
}

// 1 block, 1024 threads: final colsum over P2 (64 coalesced 4KB rows), dot,
// SQ reduce, scalar math.
__global__ __launch_bounds__(1024) void finalize3_kernel(const float* __restrict__ P2,
                                                         const float* __restrict__ SQ,
                                                         float* __restrict__ out,
                                                         int nrows) {
    const int t = threadIdx.x;
    float c = 0.f;
    #pragma unroll 8
    for (int r = 0; r < RED_BLOCKS; ++r) c += P2[(size_t)r * DIMC + t];
    float s = c * c;
    float q = SQ[t];  // GRID_A == 1024 == blockDim
    for (int off = 32; off > 0; off >>= 1) {
        s += __shfl_down(s, off, 64);
        q += __shfl_down(q, off, 64);
    }
    __shared__ float sdot[16], ssq[16];
    const int lane = t & 63, wave = t >> 6;
    if (lane == 0) { sdot[wave] = s; ssq[wave] = q; }
    __syncthreads();
    if (t == 0) {
        float dot = 0.f, sqt = 0.f;
        #pragma unroll
        for (int i = 0; i < 16; ++i) { dot += sdot[i]; sqt += ssq[i]; }
        const double pair = (double)nrows * (double)sqt - (double)dot;
        const double count = (double)nrows * (double)(nrows - 1) * 0.5;
        out[0] = (float)exp(-pair / count);
    }
}

// ---------------- fallback path (generic nrows): R1 atomic version ----------------
__global__ __launch_bounds__(256) void zero_ws_kernel(float* __restrict__ ws) {
    int idx = blockIdx.x * 256 + threadIdx.x;
    if (idx <= DIMC) ws[idx] = 0.0f;
}

__global__ __launch_bounds__(256) void partial_atomic_kernel(const float* __restrict__ feats,
                                                             float* __restrict__ ws,
                                                             int nrows) {
    const int t = threadIdx.x;
    const int col4 = t * 4;
    float4 csum = make_float4(0.f, 0.f, 0.f, 0.f);
    float sq = 0.f;
    for (int row = blockIdx.x; row < nrows; row += gridDim.x) {
        const float4 v = *reinterpret_cast<const float4*>(feats + (size_t)row * DIMC + col4);
        csum.x += v.x; csum.y += v.y; csum.z += v.z; csum.w += v.w;
        sq += v.x * v.x + v.y * v.y + v.z * v.z + v.w * v.w;
    }
    atomicAdd(&ws[col4 + 0], csum.x);
    atomicAdd(&ws[col4 + 1], csum.y);
    atomicAdd(&ws[col4 + 2], csum.z);
    atomicAdd(&ws[col4 + 3], csum.w);
    for (int off = 32; off > 0; off >>= 1) sq += __shfl_down(sq, off, 64);
    __shared__ float wsum[4];
    const int lane = t & 63, wave = t >> 6;
    if (lane == 0) wsum[wave] = sq;
    __syncthreads();
    if (t == 0) atomicAdd(&ws[DIMC], wsum[0] + wsum[1] + wsum[2] + wsum[3]);
}

__global__ __launch_bounds__(1024) void finalize_ws_kernel(const float* __restrict__ ws,
                                                           float* __restrict__ out,
                                                           int nrows) {
    const int t = threadIdx.x;
    float c = ws[t];
    float s = c * c;
    for (int off = 32; off > 0; off >>= 1) s += __shfl_down(s, off, 64);
    __shared__ float wsum[16];
    const int lane = t & 63, wave = t >> 6;
    if (lane == 0) wsum[wave] = s;
    __syncthreads();
    if (t == 0) {
        float dot = 0.f;
        #pragma unroll
        for (int i = 0; i < 16; ++i) dot += wsum[i];
        const double pair = (double)nrows * (double)ws[DIMC] - (double)dot;
        const double count = (double)nrows * (double)(nrows - 1) * 0.5;
        out[0] = (float)exp(-pair / count);
    }
}

extern "C" void kernel_launch(void* const* d_in, const int* in_sizes, int n_in,
                              void* d_out, int out_size, void* d_ws, size_t ws_size,
                              hipStream_t stream) {
    const float* feats = (const float*)d_in[0];
    float* out = (float*)d_out;
    float* ws = (float*)d_ws;
    const int nrows = in_sizes[0] / DIMC;

    float* P = ws;                                   // GRID_A*DIMC floats
    float* SQ = P + (size_t)GRID_A * DIMC;           // GRID_A floats
    float* P2 = SQ + GRID_A;                         // RED_BLOCKS*DIMC floats
    const size_t need = ((size_t)GRID_A * DIMC + GRID_A + (size_t)RED_BLOCKS * DIMC) * sizeof(float);

    if (nrows == GRID_A * ROWS_A && ws_size >= need) {
        stage1_kernel<<<GRID_A, 256, 0, stream>>>(feats, P, SQ);
        stage2_kernel<<<RED_BLOCKS, 256, 0, stream>>>(P, P2);
        finalize3_kernel<<<1, 1024, 0, stream>>>(P2, SQ, out, nrows);
    } else {
        zero_ws_kernel<<<(DIMC + 256) / 256, 256, 0, stream>>>(ws);
        partial_atomic_kernel<<<512, 256, 0, stream>>>(feats, ws, nrows);
        finalize_ws_kernel<<<1, 1024, 0, stream>>>(ws, out, nrows);
    }
}